// Round 10
// baseline (2911.263 us; speedup 1.0000x reference)
//
#include <hip/hip_runtime.h>
#include <hip/hip_bf16.h>
#include <math.h>

#define HID    512
#define BATCH  256
#define TLEN   512
#define FUT    16
#define NSTEP  (TLEN + FUT)   // 528
#define NGRP   16             // batch groups
#define WPG    16             // workgroups per group (512-thread WGs)
#define BPG    16             // batch per group
#define UPW    32             // hidden units per WG
#define NR     128            // gate rows per WG (4 gates * UPW)

// workspace byte offsets (all 256-aligned)
#define OFF_W0   0u           // packed Whh0 slices  [16][128][512]  bf16 = 2 MB
#define OFF_W1   2097152u     // packed [Wih1|Whh1]  [16][128][1024] bf16 = 4 MB
#define OFF_CA   6291456u     // activations [grp(16)][p][half][b(16)][gran][u8] bf16 = 1 MB
#define OFF_XF   7340032u     // feedback outs [FUT+1][256] f32
#define OFF_WI   7357440u     // Wih0 col packed [16][128] f32
#define OFF_B0   7365632u     // bih0+bhh0 packed [16][128] f32
#define OFF_B1   7373824u     // bih1+bhh1 packed [16][128] f32
#define OFF_BAR  7382016u     // 16 groups * 32 uints: [0..15]=flags, [16..31]=probe tokens
#define OFF_XT   7384064u     // x transposed [TLEN][BATCH] f32 = 512 KB

typedef __bf16 bf16x8 __attribute__((ext_vector_type(8)));
typedef float  f32x4  __attribute__((ext_vector_type(4)));

__device__ __forceinline__ float sigf(float v)      { return 1.f / (1.f + __expf(-v)); }
__device__ __forceinline__ float tanh_fast(float v) { return 2.f / (1.f + __expf(-2.f * v)) - 1.f; }

// ---- LLC-scope (safe anywhere) exchange ops --------------------------------
__device__ __forceinline__ void store_short_llc(void* p, unsigned short v) {
    asm volatile("global_store_short %0, %1, off sc0 sc1"
                 :: "v"(p), "v"((unsigned)v) : "memory");
}
__device__ __forceinline__ void gl2lds16_llc(const void* g, void* l) {
    __builtin_amdgcn_global_load_lds(
        (const __attribute__((address_space(1))) void*)g,
        (__attribute__((address_space(3))) void*)l, 16, 0, 17);   // sc0|sc1
}
// ---- L2-scope DATA ops (XCD-local fast path; enabled only if the runtime
//      coherence self-test passes). SESSION RULE (r2/r5/r6): flags / spin
//      polling NEVER use L2 scope. Only bulk data rides sc0. ----------------
__device__ __forceinline__ void store_short_l2(void* p, unsigned short v) {
    asm volatile("global_store_short %0, %1, off sc0"
                 :: "v"(p), "v"((unsigned)v) : "memory");
}
__device__ __forceinline__ void gl2lds16_l2(const void* g, void* l) {
    __builtin_amdgcn_global_load_lds(
        (const __attribute__((address_space(1))) void*)g,
        (__attribute__((address_space(3))) void*)l, 16, 0, 1);    // sc0 only
}
__device__ __forceinline__ void store_u32_l2(unsigned* p, unsigned v) {
    asm volatile("global_store_dword %0, %1, off sc0" :: "v"(p), "v"(v) : "memory");
}
__device__ __forceinline__ unsigned load_u32_l2(const unsigned* p) {
    unsigned v;
    asm volatile("global_load_dword %0, %1, off sc0\n\t"
                 "s_waitcnt vmcnt(0)" : "=v"(v) : "v"(p) : "memory");
    return v;
}

// flag-array barrier with OWN-FLAG SKIP. Flags ALWAYS agent-scope (LLC) --
// the r0/r4/r7-proven protocol; hang-impossible regardless of placement.
__device__ __forceinline__ void flag_barrier(unsigned* flags, int m, unsigned phase) {
    __builtin_amdgcn_s_waitcnt(0);
    __syncthreads();
    if (threadIdx.x == 0)
        __hip_atomic_store(&flags[m], phase, __ATOMIC_RELAXED, __HIP_MEMORY_SCOPE_AGENT);
    if (threadIdx.x < 64) {
        const int lane = threadIdx.x;
        const bool active = (lane < WPG) && (lane != m);
        int it = 0;
        for (;;) {
            unsigned f = phase;
            if (active)
                f = __hip_atomic_load(&flags[lane], __ATOMIC_RELAXED, __HIP_MEMORY_SCOPE_AGENT);
            if (__ballot(f >= phase) == ~0ull) break;
            if (++it > 4) __builtin_amdgcn_s_sleep(1);
        }
    }
    __syncthreads();
}

__global__ void lstm_init(char* __restrict__ ws, float* __restrict__ out,
                          const float* __restrict__ blin)
{
    float bl = blin[0];
    int tid = blockIdx.x * blockDim.x + threadIdx.x;
    int stride = gridDim.x * blockDim.x;
    uint4* ca = (uint4*)(ws + OFF_CA);
    for (int i = tid; i < 65536; i += stride) ca[i] = make_uint4(0u, 0u, 0u, 0u);
    float* xf = (float*)(ws + OFF_XF);
    for (int i = tid; i < (FUT + 1) * BATCH; i += stride) xf[i] = bl;
    unsigned* bar = (unsigned*)(ws + OFF_BAR);
    for (int i = tid; i < NGRP * 32; i += stride) bar[i] = 0u;   // flags + tokens
    for (int i = tid; i < BATCH * NSTEP; i += stride) out[i] = bl;
}

// Row packing (transpose-free ew): packed slice-row r (0..127):
//   tile T = r>>4, within-tile j = r&15 = 4*unit_local + gate
//   -> global W row = gate*HID + m*32 + T*4 + unit_local
// With weights as the FIRST mfma operand, output row = weight row:
// C-reg i of lane (fq,fl) = (unit fq, gate i) of the tile, col = fl = batch.
__device__ __forceinline__ int packed_row(int r, int m) {
    return (r & 3) * HID + m * UPW + ((r >> 4) << 2) + ((r >> 2) & 3);
}

__global__ void lstm_pack(char* __restrict__ ws,
    const float* __restrict__ x,
    const float* __restrict__ Wih0, const float* __restrict__ Whh0,
    const float* __restrict__ bih0, const float* __restrict__ bhh0,
    const float* __restrict__ Wih1, const float* __restrict__ Whh1,
    const float* __restrict__ bih1, const float* __restrict__ bhh1)
{
    int tid = blockIdx.x * blockDim.x + threadIdx.x;
    int stride = gridDim.x * blockDim.x;

    __hip_bfloat16* W0p = (__hip_bfloat16*)(ws + OFF_W0);
    for (int i = tid; i < 16 * 128 * 512; i += stride) {
        int k = i & 511, r = (i >> 9) & 127, m = i >> 16;
        int row = packed_row(r, m);
        W0p[i] = __float2bfloat16(Whh0[(size_t)row * HID + k]);
    }
    __hip_bfloat16* W1p = (__hip_bfloat16*)(ws + OFF_W1);
    for (int i = tid; i < 16 * 128 * 1024; i += stride) {
        int k = i & 1023, r = (i >> 10) & 127, m = i >> 17;
        int row = packed_row(r, m);
        float v = (k < 512) ? Wih1[(size_t)row * HID + k] : Whh1[(size_t)row * HID + (k - 512)];
        W1p[i] = __float2bfloat16(v);
    }
    float* wi = (float*)(ws + OFF_WI);
    float* b0 = (float*)(ws + OFF_B0);
    float* b1 = (float*)(ws + OFF_B1);
    for (int i = tid; i < 16 * 128; i += stride) {
        int r = i & 127, m = i >> 7;
        int row = packed_row(r, m);
        wi[i] = Wih0[row];                  // IN = 1
        b0[i] = bih0[row] + bhh0[row];
        b1[i] = bih1[row] + bhh1[row];
    }
    float* xT = (float*)(ws + OFF_XT);      // [T][B] for coalesced step reads
    for (int i = tid; i < TLEN * BATCH; i += stride) {
        int t = i >> 8, b = i & 255;
        xT[i] = x[(size_t)b * TLEN + t];
    }
}

// Pin exactly 2 waves/EU (8 waves/CU = one 512-thread WG per CU).
__global__ __attribute__((amdgpu_flat_work_group_size(512, 512),
                          amdgpu_waves_per_eu(2, 2)))
void lstm_persist(
    const float* __restrict__ wlin,
    float* __restrict__ out, char* __restrict__ ws)
{
    const int tid  = threadIdx.x;
    const int lane = tid & 63;
    const int wave = tid >> 6;         // 0..7
    const int g    = blockIdx.x & 15;  // group 0..15
    const int m    = blockIdx.x >> 4;  // member within group: unit slice 0..15
    const int bbase = g * BPG;

    // As: 16 batch-rows x 2048B: [h0 gran 0..63 | h1 gran 0..63], content
    // granule c of row r stored at granule (c + r) & 63 of its half.
    __shared__ __attribute__((aligned(16))) __hip_bfloat16 As[16 * 1024];
    // K-split partial exchange buffers (16B/lane contiguous -> conflict-free).
    // Separate L0/L1 regions so the main loop needs NO tail sync:
    //   ppA: L0 read(t) < barrier(t) < L0 write(t+1)      (barrier orders)
    //   ppB: L1 read(t) < sync1(t+1)+barrier(t+1) < L1 write(t+1)
    __shared__ __attribute__((aligned(16))) float ppA[8][256];   // 8 KB
    __shared__ __attribute__((aligned(16))) float ppB[8][256];   // 8 KB
    __shared__ float poS[2][4][17];    // double-buffered out partials
    __shared__ int l2okS;
    char* AsB = (char*)As;

    // zero As (t=0 reads h0prev=0, h1prev=0 from it)
    {
        int* az = (int*)As;
        for (int i = tid; i < (16 * 1024 * 2) / 4; i += 512) az[i] = 0;
    }

    const float* wis = (const float*)(ws + OFF_WI) + m * NR;
    const float* b0s = (const float*)(ws + OFF_B0) + m * NR;
    const float* b1s = (const float*)(ws + OFF_B1) + m * NR;
    char* CAg = ws + OFF_CA + (size_t)g * 65536;   // [parity][half][b16][gran64][u8]
    float* xfeed = (float*)(ws + OFF_XF);
    const float* xT = (const float*)(ws + OFF_XT);
    unsigned* flags = (unsigned*)(ws + OFF_BAR) + g * 32;
    unsigned* tok   = flags + 16;      // probe token slots (zeroed by init)

    const int fl = lane & 15;          // batch within group (MFMA col)
    const int fq = lane >> 4;          // k-sub-chunk on inputs / unit on output
    const int kh = wave >> 2;          // K-half this wave computes (0/1)
    const int wp = wave & 3;           // pair index: tiles 2wp, 2wp+1

    // kh0 waves own ew for tiles 2wp,2wp+1: per-lane units uloc_t = (2wp+t)*4+fq
    float4 wiV[2], b0V[2], b1V[2];
    float  wl0[2];
    int    pub[2];
#pragma unroll
    for (int t2 = 0; t2 < 2; ++t2) {
        const int T = 2 * wp + t2;
        wiV[t2] = *(const float4*)(wis + T * 16 + fq * 4);
        b0V[t2] = *(const float4*)(b0s + T * 16 + fq * 4);
        b1V[t2] = *(const float4*)(b1s + T * 16 + fq * 4);
        const int uloc = T * 4 + fq;
        wl0[t2] = wlin[m * UPW + uloc];
        const int cgr = 4 * m + (uloc >> 3);
        pub[t2] = fl * 1024 + (((cgr + fl) & 63) << 4) + (uloc & 7) * 2;
    }
    float c00[2] = {0.f, 0.f}, c10[2] = {0.f, 0.f};

    // ---- weight frags: wave owns tiles 2wp,2wp+1 x K-half kh.
    //      48 bf16x8 frags/lane = 192 regs (r7-proven budget).
    const bf16x8* W0base = (const bf16x8*)(ws + OFF_W0 + (size_t)m * NR * 512 * 2);
    const bf16x8* W1base = (const bf16x8*)(ws + OFF_W1 + (size_t)m * NR * 1024 * 2);
    bf16x8 w0f[2][8], w1f[2][16];
#pragma unroll
    for (int t2 = 0; t2 < 2; ++t2) {
        const int row = (2 * wp + t2) * 16 + fl;
#pragma unroll
        for (int j = 0; j < 8; ++j)
            w0f[t2][j] = W0base[(size_t)row * 64 + (kh * 8 + j) * 4 + fq];
#pragma unroll
        for (int j = 0; j < 16; ++j)
            w1f[t2][j] = W1base[(size_t)row * 128 + (kh * 16 + j) * 4 + fq];
    }

    __syncthreads();  // As zeroed before use

    // ---- functional coherence self-test for sc0 DATA path (r4-proven).
    unsigned phase = 0;
    {
        if (tid == 0) store_u32_l2(&tok[m], 0xA5000000u | (unsigned)m);
        ++phase; flag_barrier(flags, m, phase);
        if (tid < 64) {
            const bool act = (tid < WPG);
            unsigned v = act ? load_u32_l2(&tok[tid]) : 0u;
            int eq = act ? (v == (0xA5000000u | (unsigned)tid)) : 1;
            unsigned long long bal = __ballot(eq);
            if (tid == 0) l2okS = (bal == ~0ull) ? 1 : 0;
        }
        __syncthreads();
        if (tid == 0) store_u32_l2(&tok[m], 0x5A110000u | (unsigned)m);
        ++phase; flag_barrier(flags, m, phase);
        if (tid < 64) {
            const bool act = (tid < WPG);
            unsigned v = act ? load_u32_l2(&tok[tid]) : 0u;
            int eq = act ? (v == (0x5A110000u | (unsigned)tid)) : 1;
            unsigned long long bal = __ballot(eq);
            if (tid == 0 && bal != ~0ull) l2okS = 0;
        }
        __syncthreads();
    }
    const bool l2ok = (l2okS != 0);

    const bf16x8* Asv = (const bf16x8*)As;   // 16 batch-rows x 128 granules

    for (int t = 0; t < NSTEP; ++t) {
        const int p = t & 1;
        char* CAp = CAg + p * 32768;          // this step's parity (h0/h1 writes)
        char* CAq = CAg + (1 - p) * 32768;    // previous parity (h1prev reads)

        float xv0;
        if (t < TLEN) {
            xv0 = xT[t * BATCH + bbase + fl];
        } else {
            xv0 = xfeed[(t - TLEN) * BATCH + bbase + fl];
        }

        // ---------------- layer 0 GEMM: tiles 2wp,2wp+1 x K-half kh.
        // 8 A-reads feed 16 MFMAs (2 indep chains). mfma(W,H): row=gates.
        f32x4 acc0 = {0.f, 0.f, 0.f, 0.f};
        f32x4 acc1 = {0.f, 0.f, 0.f, 0.f};
#pragma unroll
        for (int j = 0; j < 8; ++j) {
            bf16x8 a0 = Asv[fl * 128 + ((kh * 32 + j * 4 + fq + fl) & 63)];
            acc0 = __builtin_amdgcn_mfma_f32_16x16x32_bf16(w0f[0][j], a0, acc0, 0, 0, 0);
            acc1 = __builtin_amdgcn_mfma_f32_16x16x32_bf16(w0f[1][j], a0, acc1, 0, 0, 0);
        }
        if (kh == 1) {                      // publish K-half-1 partials
            *(f32x4*)&ppA[wp * 2 + 0][lane * 4] = acc0;
            *(f32x4*)&ppA[wp * 2 + 1][lane * 4] = acc1;
        }
        __syncthreads();                    // sync1: ppA writes -> kh0 reads

        // ---------------- layer 0 elementwise (kh0 waves, lane-local gates)
        if (kh == 0) {
            f32x4 q0 = *(const f32x4*)&ppA[wp * 2 + 0][lane * 4];
            f32x4 q1 = *(const f32x4*)&ppA[wp * 2 + 1][lane * 4];
            acc0 += q0; acc1 += q1;
#pragma unroll
            for (int t2 = 0; t2 < 2; ++t2) {
                f32x4 a = t2 ? acc1 : acc0;
                float gi = a[0] + b0V[t2].x + xv0 * wiV[t2].x;
                float gf = a[1] + b0V[t2].y + xv0 * wiV[t2].y;
                float gg = a[2] + b0V[t2].z + xv0 * wiV[t2].z;
                float go = a[3] + b0V[t2].w + xv0 * wiV[t2].w;
                c00[t2] = sigf(gf) * c00[t2] + sigf(gi) * tanh_fast(gg);
                __hip_bfloat16 h = __float2bfloat16(sigf(go) * tanh_fast(c00[t2]));
                if (l2ok) store_short_l2 (CAp + pub[t2], *(unsigned short*)&h);
                else      store_short_llc(CAp + pub[t2], *(unsigned short*)&h);
            }
        }

        ++phase;
        flag_barrier(flags, m, phase);   // h0(t) + h1(t-1) publish -> all WGs

        // ---------------- stage [h0new | h1prev] -> LDS As (async DMA)
#pragma unroll
        for (int ci = 0; ci < 2; ++ci) {
            int b = wave * 2 + ci;
            if (l2ok) {
                gl2lds16_l2 (CAp + b * 1024 + lane * 16,
                             AsB + b * 2048 + lane * 16);            // h0 new
                gl2lds16_l2 (CAq + 16384 + b * 1024 + lane * 16,
                             AsB + b * 2048 + 1024 + lane * 16);     // h1 prev
            } else {
                gl2lds16_llc(CAp + b * 1024 + lane * 16,
                             AsB + b * 2048 + lane * 16);
                gl2lds16_llc(CAq + 16384 + b * 1024 + lane * 16,
                             AsB + b * 2048 + 1024 + lane * 16);
            }
        }
        // deferred out-finish for step t-1 (main region) -- overlaps DMA flight.
        // poS[(t-1)&1] writes (ew1(t-1), after sync3) are ordered by sync1(t)
        // + barrier(t); buffer not rewritten until ew1(t+1).
        if (t >= 1 && t < TLEN) {
            if (wave == 0 && lane < 16) {
                const int q = (t - 1) & 1;
                float s = poS[q][0][lane] + poS[q][1][lane]
                        + poS[q][2][lane] + poS[q][3][lane];
                atomicAdd(&out[(size_t)(bbase + lane) * NSTEP + (t - 1)], s);
            }
        }
        __builtin_amdgcn_s_waitcnt(0);
        __syncthreads();             // stage-sync: DMA -> LDS reads

        // ---------------- layer 1 GEMM: K=1024 split; kh0 -> h0 half,
        // kh1 -> h1 half. 16 A-reads feed 32 MFMAs.
        acc0 = (f32x4){0.f, 0.f, 0.f, 0.f};
        acc1 = (f32x4){0.f, 0.f, 0.f, 0.f};
#pragma unroll
        for (int j = 0; j < 16; ++j) {
            bf16x8 a0 = Asv[fl * 128 + kh * 64 + ((j * 4 + fq + fl) & 63)];
            acc0 = __builtin_amdgcn_mfma_f32_16x16x32_bf16(w1f[0][j], a0, acc0, 0, 0, 0);
            acc1 = __builtin_amdgcn_mfma_f32_16x16x32_bf16(w1f[1][j], a0, acc1, 0, 0, 0);
        }
        if (kh == 1) {
            *(f32x4*)&ppB[wp * 2 + 0][lane * 4] = acc0;
            *(f32x4*)&ppB[wp * 2 + 1][lane * 4] = acc1;
        }
        __syncthreads();                    // sync3: ppB writes -> kh0 reads

        // ---------------- layer 1 elementwise + OUT=1 linear (kh0 waves)
        if (kh == 0) {
            f32x4 q0 = *(const f32x4*)&ppB[wp * 2 + 0][lane * 4];
            f32x4 q1 = *(const f32x4*)&ppB[wp * 2 + 1][lane * 4];
            acc0 += q0; acc1 += q1;
            float po = 0.f;
#pragma unroll
            for (int t2 = 0; t2 < 2; ++t2) {
                f32x4 a = t2 ? acc1 : acc0;
                float gi = a[0] + b1V[t2].x;
                float gf = a[1] + b1V[t2].y;
                float gg = a[2] + b1V[t2].z;
                float go = a[3] + b1V[t2].w;
                c10[t2] = sigf(gf) * c10[t2] + sigf(gi) * tanh_fast(gg);
                float h = sigf(go) * tanh_fast(c10[t2]);
                __hip_bfloat16 hb = __float2bfloat16(h);
                if (l2ok) store_short_l2 (CAp + 16384 + pub[t2], *(unsigned short*)&hb);
                else      store_short_llc(CAp + 16384 + pub[t2], *(unsigned short*)&hb);
                po += wl0[t2] * h;
            }
            po += __shfl_xor(po, 16, 64);   // sum the 4 fq (units) of this wave
            po += __shfl_xor(po, 32, 64);
            if (lane < 16) poS[t & 1][wp][lane] = po;
        }

        // Main region: NO tail sync (ppA/ppB split + barrier ordering cover all
        // cross-iteration hazards; finish is deferred). FUT region: immediate
        // finish + inter-WG barrier (xfeed must be visible before next read).
        if (t >= TLEN - 1) {
            __syncthreads();               // poS writes -> finish reads
            if (wave == 0 && lane < 16) {
                const int q = t & 1;
                float s = poS[q][0][lane] + poS[q][1][lane]
                        + poS[q][2][lane] + poS[q][3][lane];
                atomicAdd(&out[(size_t)(bbase + lane) * NSTEP + t], s);
                atomicAdd(&xfeed[(t - (TLEN - 1)) * BATCH + bbase + lane], s);
            }
            ++phase;
            flag_barrier(flags, m, phase);
        }
    }
}

extern "C" void kernel_launch(void* const* d_in, const int* in_sizes, int n_in,
                              void* d_out, int out_size, void* d_ws, size_t ws_size,
                              hipStream_t stream)
{
    const float* x    = (const float*)d_in[0];
    const float* Wih0 = (const float*)d_in[1];
    const float* Whh0 = (const float*)d_in[2];
    const float* bih0 = (const float*)d_in[3];
    const float* bhh0 = (const float*)d_in[4];
    const float* Wih1 = (const float*)d_in[5];
    const float* Whh1 = (const float*)d_in[6];
    const float* bih1 = (const float*)d_in[7];
    const float* bhh1 = (const float*)d_in[8];
    const float* Wlin = (const float*)d_in[9];
    const float* blin = (const float*)d_in[10];
    float* out = (float*)d_out;
    char* ws = (char*)d_ws;

    hipLaunchKernelGGL(lstm_init, dim3(256), dim3(256), 0, stream, ws, out, blin);
    hipLaunchKernelGGL(lstm_pack, dim3(512), dim3(256), 0, stream,
                       ws, x, Wih0, Whh0, bih0, bhh0, Wih1, Whh1, bih1, bhh1);
    hipLaunchKernelGGL(lstm_persist, dim3(256), dim3(512), 0, stream, Wlin, out, ws);
}

// Round 11
// 1994.639 us; speedup vs baseline: 1.4595x; 1.4595x over previous
//
#include <hip/hip_runtime.h>
#include <hip/hip_bf16.h>
#include <math.h>

#define HID    512
#define BATCH  256
#define TLEN   512
#define FUT    16
#define NSTEP  (TLEN + FUT)   // 528
#define NGRP   16             // batch groups
#define WPG    16             // workgroups per group (512-thread WGs)
#define BPG    16             // batch per group
#define UPW    32             // hidden units per WG
#define NR     128            // gate rows per WG (4 gates * UPW)

// workspace byte offsets (all 256-aligned)
#define OFF_W0   0u           // packed Whh0 slices  [16][128][512]  bf16 = 2 MB
#define OFF_W1   2097152u     // packed [Wih1|Whh1]  [16][128][1024] bf16 = 4 MB
#define OFF_CA   6291456u     // activations [grp(16)][p][half][b(16)][gran][u8] bf16 = 1 MB
#define OFF_XF   7340032u     // feedback outs [FUT+1][256] f32
#define OFF_WI   7357440u     // Wih0 col packed [16][128] f32
#define OFF_B0   7365632u     // bih0+bhh0 packed [16][128] f32
#define OFF_B1   7373824u     // bih1+bhh1 packed [16][128] f32
#define OFF_BAR  7382016u     // 16 groups * 32 uints: [0..15]=flags, [16..31]=probe tokens
#define OFF_XT   7384064u     // x transposed [TLEN][BATCH] f32 = 512 KB

typedef __bf16 bf16x8 __attribute__((ext_vector_type(8)));
typedef float  f32x4  __attribute__((ext_vector_type(4)));

__device__ __forceinline__ float sigf(float v)      { return 1.f / (1.f + __expf(-v)); }
__device__ __forceinline__ float tanh_fast(float v) { return 2.f / (1.f + __expf(-2.f * v)) - 1.f; }

// ---- LLC-scope (safe anywhere) exchange ops --------------------------------
__device__ __forceinline__ void store_short_llc(void* p, unsigned short v) {
    asm volatile("global_store_short %0, %1, off sc0 sc1"
                 :: "v"(p), "v"((unsigned)v) : "memory");
}
__device__ __forceinline__ void gl2lds16_llc(const void* g, void* l) {
    __builtin_amdgcn_global_load_lds(
        (const __attribute__((address_space(1))) void*)g,
        (__attribute__((address_space(3))) void*)l, 16, 0, 17);   // sc0|sc1
}
// ---- L2-scope DATA ops (XCD-local fast path; enabled only if the runtime
//      coherence self-test passes). SESSION RULE (r2/r5/r6): flags / spin
//      polling NEVER use L2 scope. Only bulk data rides sc0. ----------------
__device__ __forceinline__ void store_short_l2(void* p, unsigned short v) {
    asm volatile("global_store_short %0, %1, off sc0"
                 :: "v"(p), "v"((unsigned)v) : "memory");
}
__device__ __forceinline__ void gl2lds16_l2(const void* g, void* l) {
    __builtin_amdgcn_global_load_lds(
        (const __attribute__((address_space(1))) void*)g,
        (__attribute__((address_space(3))) void*)l, 16, 0, 1);    // sc0 only
}
__device__ __forceinline__ void store_u32_l2(unsigned* p, unsigned v) {
    asm volatile("global_store_dword %0, %1, off sc0" :: "v"(p), "v"(v) : "memory");
}
__device__ __forceinline__ unsigned load_u32_l2(const unsigned* p) {
    unsigned v;
    asm volatile("global_load_dword %0, %1, off sc0\n\t"
                 "s_waitcnt vmcnt(0)" : "=v"(v) : "v"(p) : "memory");
    return v;
}

// flag-array barrier with OWN-FLAG SKIP. Flags ALWAYS agent-scope (LLC) --
// the r0/r4/r7-proven protocol; hang-impossible regardless of placement.
__device__ __forceinline__ void flag_barrier(unsigned* flags, int m, unsigned phase) {
    __builtin_amdgcn_s_waitcnt(0);
    __syncthreads();
    if (threadIdx.x == 0)
        __hip_atomic_store(&flags[m], phase, __ATOMIC_RELAXED, __HIP_MEMORY_SCOPE_AGENT);
    if (threadIdx.x < 64) {
        const int lane = threadIdx.x;
        const bool active = (lane < WPG) && (lane != m);
        int it = 0;
        for (;;) {
            unsigned f = phase;
            if (active)
                f = __hip_atomic_load(&flags[lane], __ATOMIC_RELAXED, __HIP_MEMORY_SCOPE_AGENT);
            if (__ballot(f >= phase) == ~0ull) break;
            if (++it > 4) __builtin_amdgcn_s_sleep(1);
        }
    }
    __syncthreads();
}

__global__ void lstm_init(char* __restrict__ ws, float* __restrict__ out,
                          const float* __restrict__ blin)
{
    float bl = blin[0];
    int tid = blockIdx.x * blockDim.x + threadIdx.x;
    int stride = gridDim.x * blockDim.x;
    uint4* ca = (uint4*)(ws + OFF_CA);
    for (int i = tid; i < 65536; i += stride) ca[i] = make_uint4(0u, 0u, 0u, 0u);
    float* xf = (float*)(ws + OFF_XF);
    for (int i = tid; i < (FUT + 1) * BATCH; i += stride) xf[i] = bl;
    unsigned* bar = (unsigned*)(ws + OFF_BAR);
    for (int i = tid; i < NGRP * 32; i += stride) bar[i] = 0u;   // flags + tokens
    for (int i = tid; i < BATCH * NSTEP; i += stride) out[i] = bl;
}

// Row packing (transpose-free ew): packed slice-row r (0..127):
//   tile T = r>>4, within-tile j = r&15 = 4*unit_local + gate
//   -> global W row = gate*HID + m*32 + T*4 + unit_local
// With weights as the FIRST mfma operand, output row = weight row:
// C-reg i of lane (fq,fl) = (unit fq, gate i) of the tile, col = fl = batch.
__device__ __forceinline__ int packed_row(int r, int m) {
    return (r & 3) * HID + m * UPW + ((r >> 4) << 2) + ((r >> 2) & 3);
}

__global__ void lstm_pack(char* __restrict__ ws,
    const float* __restrict__ x,
    const float* __restrict__ Wih0, const float* __restrict__ Whh0,
    const float* __restrict__ bih0, const float* __restrict__ bhh0,
    const float* __restrict__ Wih1, const float* __restrict__ Whh1,
    const float* __restrict__ bih1, const float* __restrict__ bhh1)
{
    int tid = blockIdx.x * blockDim.x + threadIdx.x;
    int stride = gridDim.x * blockDim.x;

    __hip_bfloat16* W0p = (__hip_bfloat16*)(ws + OFF_W0);
    for (int i = tid; i < 16 * 128 * 512; i += stride) {
        int k = i & 511, r = (i >> 9) & 127, m = i >> 16;
        int row = packed_row(r, m);
        W0p[i] = __float2bfloat16(Whh0[(size_t)row * HID + k]);
    }
    __hip_bfloat16* W1p = (__hip_bfloat16*)(ws + OFF_W1);
    for (int i = tid; i < 16 * 128 * 1024; i += stride) {
        int k = i & 1023, r = (i >> 10) & 127, m = i >> 17;
        int row = packed_row(r, m);
        float v = (k < 512) ? Wih1[(size_t)row * HID + k] : Whh1[(size_t)row * HID + (k - 512)];
        W1p[i] = __float2bfloat16(v);
    }
    float* wi = (float*)(ws + OFF_WI);
    float* b0 = (float*)(ws + OFF_B0);
    float* b1 = (float*)(ws + OFF_B1);
    for (int i = tid; i < 16 * 128; i += stride) {
        int r = i & 127, m = i >> 7;
        int row = packed_row(r, m);
        wi[i] = Wih0[row];                  // IN = 1
        b0[i] = bih0[row] + bhh0[row];
        b1[i] = bih1[row] + bhh1[row];
    }
    float* xT = (float*)(ws + OFF_XT);      // [T][B] for coalesced step reads
    for (int i = tid; i < TLEN * BATCH; i += stride) {
        int t = i >> 8, b = i & 255;
        xT[i] = x[(size_t)b * TLEN + t];
    }
}

// Pin exactly 2 waves/EU (8 waves/CU = one 512-thread WG per CU) -> 256 VGPR
// budget per lane. The in-loop asm pins below force the 48 weight fragments
// (192 VGPRs) to stay register-resident instead of being re-streamed from L2
// every timestep (all prior builds compiled to VGPR_Count=128, which cannot
// hold them -- suspected ~96 MB/step of L2 weight re-reads as the real floor).
__global__ __attribute__((amdgpu_flat_work_group_size(512, 512),
                          amdgpu_waves_per_eu(2, 2)))
void lstm_persist(
    const float* __restrict__ wlin,
    float* __restrict__ out, char* __restrict__ ws)
{
    const int tid  = threadIdx.x;
    const int lane = tid & 63;
    const int wave = tid >> 6;         // 0..7 = row-tile owner
    const int g    = blockIdx.x & 15;  // group 0..15
    const int m    = blockIdx.x >> 4;  // member within group: unit slice 0..15
    const int bbase = g * BPG;

    // As: 16 rows x 2048B; row r = batch r: [h0 gran 0..63 | h1 gran 0..63],
    // content granule c stored at granule (c + r) & 63 of its half (swizzle).
    __shared__ __attribute__((aligned(16))) __hip_bfloat16 As[16 * 1024];
    __shared__ float poS[8][17];       // per-wave out partials (pad -> no conflict)
    __shared__ int l2okS;
    char* AsB = (char*)As;

    // zero As (t=0 reads h0prev=0, h1prev=0 from it)
    {
        int* az = (int*)As;
        for (int i = tid; i < (16 * 1024 * 2) / 4; i += 512) az[i] = 0;
    }

    const float* wis = (const float*)(ws + OFF_WI) + m * NR;
    const float* b0s = (const float*)(ws + OFF_B0) + m * NR;
    const float* b1s = (const float*)(ws + OFF_B1) + m * NR;
    char* CAg = ws + OFF_CA + (size_t)g * 65536;   // [parity][half][b16][gran64][u8]
    float* xfeed = (float*)(ws + OFF_XF);
    const float* xT = (const float*)(ws + OFF_XT);
    unsigned* flags = (unsigned*)(ws + OFF_BAR) + g * 32;
    unsigned* tok   = flags + 16;      // probe token slots (zeroed by init)

    const int fl = lane & 15;          // batch within group (MFMA col / B operand)
    const int fq = lane >> 4;          // quad: k-sub-chunk on inputs, unit on output
    const int uloc = wave * 4 + fq;    // this lane's unit within the 32-unit slice

    // per-lane per-unit parameters: packed index wave*16 + fq*4 + gate
    const float4 wiV = *(const float4*)(wis + wave * 16 + fq * 4);
    const float4 b0V = *(const float4*)(b0s + wave * 16 + fq * 4);
    const float4 b1V = *(const float4*)(b1s + wave * 16 + fq * 4);
    const float wl0  = wlin[m * UPW + uloc];
    float c00 = 0.f, c10 = 0.f;        // cell state for (uloc, fl)

    // publish byte offset for (unit uloc, batch fl), within a CA half:
    // content granule c = 4m + (uloc>>3); batch row b -> granule (c+b)&63.
    const int cgr  = 4 * m + (uloc >> 3);
    const int pub0 = fl * 1024 + (((cgr + fl) & 63) << 4) + (uloc & 7) * 2;

    // ---- weight frags: wave owns ONE 16-row tile, full K.
    //      48 bf16x8 frags/lane = 192 VGPRs. Weight row (wave*16+fl) is the
    //      A-operand row; fq selects the k-sub-chunk.
    const bf16x8* W0row = (const bf16x8*)(ws + OFF_W0 + (size_t)m * NR * 512 * 2)
                          + (size_t)(wave * 16 + fl) * 64;
    const bf16x8* W1row = (const bf16x8*)(ws + OFF_W1 + (size_t)m * NR * 1024 * 2)
                          + (size_t)(wave * 16 + fl) * 128;
    bf16x8 w0f[16], w1f[32];
#pragma unroll
    for (int ks = 0; ks < 16; ++ks) w0f[ks] = W0row[ks * 4 + fq];
#pragma unroll
    for (int ks = 0; ks < 32; ++ks) w1f[ks] = W1row[ks * 4 + fq];

    __syncthreads();  // As zeroed before use

    // ---- functional coherence self-test for sc0 DATA path (r4-proven).
    //      Probe barriers agent-only -> cannot hang; verdicts cannot mix
    //      (sc0 visibility symmetric: one cross-XCD member fails ALL).
    unsigned phase = 0;
    {
        if (tid == 0) store_u32_l2(&tok[m], 0xA5000000u | (unsigned)m);
        ++phase; flag_barrier(flags, m, phase);
        if (tid < 64) {
            const bool act = (tid < WPG);
            unsigned v = act ? load_u32_l2(&tok[tid]) : 0u;
            int eq = act ? (v == (0xA5000000u | (unsigned)tid)) : 1;
            unsigned long long bal = __ballot(eq);
            if (tid == 0) l2okS = (bal == ~0ull) ? 1 : 0;
        }
        __syncthreads();
        if (tid == 0) store_u32_l2(&tok[m], 0x5A110000u | (unsigned)m);
        ++phase; flag_barrier(flags, m, phase);
        if (tid < 64) {
            const bool act = (tid < WPG);
            unsigned v = act ? load_u32_l2(&tok[tid]) : 0u;
            int eq = act ? (v == (0x5A110000u | (unsigned)tid)) : 1;
            unsigned long long bal = __ballot(eq);
            if (tid == 0 && bal != ~0ull) l2okS = 0;
        }
        __syncthreads();
    }
    const bool l2ok = (l2okS != 0);

    const bf16x8* Asv = (const bf16x8*)As;   // 16 batch-rows x 128 granules

    for (int t = 0; t < NSTEP; ++t) {
        // ---- REGISTER PIN: opaque touch of every weight fragment each
        // iteration. The asm "writes" the value, so re-loading it from L2
        // would be ILLEGAL for the compiler -> the 48 frags must stay live
        // in registers across the whole loop body (spill-to-scratch is the
        // only alternative, visible as a dur regression). Zero instructions
        // emitted; bit-cast round trip avoids address-taking.
#pragma unroll
        for (int ks = 0; ks < 16; ++ks) {
            f32x4 tmp = __builtin_bit_cast(f32x4, w0f[ks]);
            asm volatile("" : "+v"(tmp));
            w0f[ks] = __builtin_bit_cast(bf16x8, tmp);
        }
#pragma unroll
        for (int ks = 0; ks < 32; ++ks) {
            f32x4 tmp = __builtin_bit_cast(f32x4, w1f[ks]);
            asm volatile("" : "+v"(tmp));
            w1f[ks] = __builtin_bit_cast(bf16x8, tmp);
        }

        const int p = t & 1;
        char* CAp = CAg + p * 32768;          // this step's parity (h0/h1 writes)
        char* CAq = CAg + (1 - p) * 32768;    // previous parity (h1prev reads)

        float xv0;
        if (t < TLEN) {
            xv0 = xT[t * BATCH + bbase + fl];
        } else {
            xv0 = xfeed[(t - TLEN) * BATCH + bbase + fl];
        }

        // ---------------- layer 0 GEMM from LDS (h0prev, half 0), full K.
        // SWAPPED operands: mfma(W, H) -> output row = weight row (lane-local
        // gates), col = batch. 16 A-reads, two 8-deep chains, summed at end.
        f32x4 aA = {0.f, 0.f, 0.f, 0.f};
        f32x4 aB = {0.f, 0.f, 0.f, 0.f};
#pragma unroll
        for (int j = 0; j < 8; ++j) {
            bf16x8 a0 = Asv[fl * 128 + ((j * 4 + fq + fl) & 63)];
            aA = __builtin_amdgcn_mfma_f32_16x16x32_bf16(w0f[j], a0, aA, 0, 0, 0);
        }
#pragma unroll
        for (int j = 8; j < 16; ++j) {
            bf16x8 a0 = Asv[fl * 128 + ((j * 4 + fq + fl) & 63)];
            aB = __builtin_amdgcn_mfma_f32_16x16x32_bf16(w0f[j], a0, aB, 0, 0, 0);
        }

        // ---------------- layer 0 elementwise -- fully lane-local:
        // reg i of the C-frag IS gate i (i,f,g,o) of unit uloc, batch fl.
        {
            float gi = aA[0] + aB[0] + b0V.x + xv0 * wiV.x;
            float gf = aA[1] + aB[1] + b0V.y + xv0 * wiV.y;
            float gg = aA[2] + aB[2] + b0V.z + xv0 * wiV.z;
            float go = aA[3] + aB[3] + b0V.w + xv0 * wiV.w;
            c00 = sigf(gf) * c00 + sigf(gi) * tanh_fast(gg);
            __hip_bfloat16 h = __float2bfloat16(sigf(go) * tanh_fast(c00));
            if (l2ok) store_short_l2 (CAp + pub0, *(unsigned short*)&h);
            else      store_short_llc(CAp + pub0, *(unsigned short*)&h);
        }

        ++phase;
        flag_barrier(flags, m, phase);   // h0(t) + h1(t-1) publish -> all WGs

        // ---------------- stage [h0new | h1prev] -> LDS As (1KB DMA per row/half)
        {
#pragma unroll
            for (int ci = 0; ci < 2; ++ci) {
                int b = wave * 2 + ci;
                if (l2ok) {
                    gl2lds16_l2 (CAp + b * 1024 + lane * 16,
                                 AsB + b * 2048 + lane * 16);            // h0 new
                    gl2lds16_l2 (CAq + 16384 + b * 1024 + lane * 16,
                                 AsB + b * 2048 + 1024 + lane * 16);     // h1 prev
                } else {
                    gl2lds16_llc(CAp + b * 1024 + lane * 16,
                                 AsB + b * 2048 + lane * 16);
                    gl2lds16_llc(CAq + 16384 + b * 1024 + lane * 16,
                                 AsB + b * 2048 + 1024 + lane * 16);
                }
            }
            __builtin_amdgcn_s_waitcnt(0);
            __syncthreads();             // sync: DMA -> LDS reads
        }

        // ---------------- layer 1 GEMM: K=1024 over [h0new | h1prev], full K.
        // 32 A-reads, two 16-deep chains (h0 half / h1 half), summed at end.
        aA = (f32x4){0.f, 0.f, 0.f, 0.f};
        aB = (f32x4){0.f, 0.f, 0.f, 0.f};
#pragma unroll
        for (int j = 0; j < 16; ++j) {
            bf16x8 a0 = Asv[fl * 128 + ((j * 4 + fq + fl) & 63)];
            aA = __builtin_amdgcn_mfma_f32_16x16x32_bf16(w1f[j], a0, aA, 0, 0, 0);
        }
#pragma unroll
        for (int j = 16; j < 32; ++j) {
            bf16x8 a0 = Asv[fl * 128 + 64 + (((j - 16) * 4 + fq + fl) & 63)];
            aB = __builtin_amdgcn_mfma_f32_16x16x32_bf16(w1f[j], a0, aB, 0, 0, 0);
        }

        // ---------------- layer 1 elementwise + OUT=1 linear, lane-local
        {
            float gi = aA[0] + aB[0] + b1V.x;
            float gf = aA[1] + aB[1] + b1V.y;
            float gg = aA[2] + aB[2] + b1V.z;
            float go = aA[3] + aB[3] + b1V.w;
            c10 = sigf(gf) * c10 + sigf(gi) * tanh_fast(gg);
            float h = sigf(go) * tanh_fast(c10);
            __hip_bfloat16 hb = __float2bfloat16(h);
            if (l2ok) store_short_l2 (CAp + 16384 + pub0, *(unsigned short*)&hb);
            else      store_short_llc(CAp + 16384 + pub0, *(unsigned short*)&hb);
            float po = wl0 * h;
            po += __shfl_xor(po, 16, 64);     // sum the 4 fq (units) of this wave
            po += __shfl_xor(po, 32, 64);
            if (lane < 16) poS[wave][lane] = po;   // per-wave partial for batch=lane
        }
        __syncthreads();               // tail: poS writes -> finish reads

        // finish: wave 0 sums the 8 wave-partials per batch, one atomic each.
        // (Placement matters: issued here, the atomic retires under the next
        //  step's L0 GEMM before the following flag_barrier's waitcnt -- the
        //  r10 regression came from issuing it right before a waitcnt(0).)
        if (wave == 0 && lane < 16) {
            float s = poS[0][lane] + poS[1][lane] + poS[2][lane] + poS[3][lane]
                    + poS[4][lane] + poS[5][lane] + poS[6][lane] + poS[7][lane];
            atomicAdd(&out[(size_t)(bbase + lane) * NSTEP + t], s);
            if (t >= TLEN - 1)
                atomicAdd(&xfeed[(t - (TLEN - 1)) * BATCH + bbase + lane], s);
        }

        // FUT region: inter-WG barrier so xfeed atomics are globally visible
        // before next step's ew0 feedback reads (and h1 ordering as before).
        if (t >= TLEN - 1) {
            ++phase;
            flag_barrier(flags, m, phase);
        }
    }
}

extern "C" void kernel_launch(void* const* d_in, const int* in_sizes, int n_in,
                              void* d_out, int out_size, void* d_ws, size_t ws_size,
                              hipStream_t stream)
{
    const float* x    = (const float*)d_in[0];
    const float* Wih0 = (const float*)d_in[1];
    const float* Whh0 = (const float*)d_in[2];
    const float* bih0 = (const float*)d_in[3];
    const float* bhh0 = (const float*)d_in[4];
    const float* Wih1 = (const float*)d_in[5];
    const float* Whh1 = (const float*)d_in[6];
    const float* bih1 = (const float*)d_in[7];
    const float* bhh1 = (const float*)d_in[8];
    const float* Wlin = (const float*)d_in[9];
    const float* blin = (const float*)d_in[10];
    float* out = (float*)d_out;
    char* ws = (char*)d_ws;

    hipLaunchKernelGGL(lstm_init, dim3(256), dim3(256), 0, stream, ws, out, blin);
    hipLaunchKernelGGL(lstm_pack, dim3(512), dim3(256), 0, stream,
                       ws, x, Wih0, Whh0, bih0, bhh0, Wih1, Whh1, bih1, bhh1);
    hipLaunchKernelGGL(lstm_persist, dim3(256), dim3(512), 0, stream, Wlin, out, ws);
}